// Round 13
// baseline (215.382 us; speedup 1.0000x reference)
//
#include <hip/hip_runtime.h>
#include <hip/hip_bf16.h>

#define DIM 128
#define SEQ 8192
#define NSPLIT 8
#define SPLITLEN (SEQ / NSPLIT)        // 1024
#define NT64 (SPLITLEN / 64)           // 16
#define NBLOCKS 512
#define SCALE_L2E 0.1275325340249306f  // (1/sqrt(128)) * log2(e)
#define PSTR 72

// ws layout (bytes): opb u64 [NSPLIT][SEQ][32] | lp f32 [NSPLIT][SEQ] | Kst | Vst | bar
#define OPB_BYTES ((size_t)NSPLIT * SEQ * 32 * 8)       // 16777216
#define LP_BYTE   OPB_BYTES
#define KST_BYTE  (LP_BYTE + (size_t)NSPLIT * SEQ * 4)  // 17039360
#define VST_BYTE  (KST_BYTE + (size_t)SEQ * DIM * 2)    // 19136512
#define BAR_BYTE  (VST_BYTE + (size_t)SEQ * DIM * 2)    // 21233664
#define WS_NEED   (BAR_BYTE + 128)

typedef __attribute__((ext_vector_type(8))) short short8;
typedef __attribute__((ext_vector_type(4))) float f32x4;
typedef __attribute__((ext_vector_type(16))) float f32x16;

__device__ __forceinline__ unsigned short f2bf(float f) {
  return __builtin_bit_cast(unsigned short, __float2bfloat16(f));
}
__device__ __forceinline__ unsigned int f2bf2(float a, float b) {
  return (unsigned int)f2bf(a) | ((unsigned int)f2bf(b) << 16);
}
__device__ __forceinline__ float bf2f(unsigned short u) {
  return __builtin_bit_cast(float, (unsigned int)u << 16);
}
__device__ __forceinline__ float fast_exp2(float x) {
#if __has_builtin(__builtin_amdgcn_exp2f)
  return __builtin_amdgcn_exp2f(x);
#else
  return exp2f(x);
#endif
}
__device__ __forceinline__ void async_cp16(const void* g, void* l) {
  __builtin_amdgcn_global_load_lds(
      (const __attribute__((address_space(1))) void*)g,
      (__attribute__((address_space(3))) void*)l, 16, 0, 0);
}

// grid barrier: all 512 blocks co-resident (LDS 51200 -> 3 blk/CU capacity, 2 launched)
__device__ __forceinline__ void gbar(unsigned int* cnt) {
  __syncthreads();
  if (threadIdx.x == 0) {
    __threadfence();  // agent release: drain + make prior writes visible
    __hip_atomic_fetch_add(cnt, 1u, __ATOMIC_ACQ_REL, __HIP_MEMORY_SCOPE_AGENT);
    while (__hip_atomic_load(cnt, __ATOMIC_ACQUIRE, __HIP_MEMORY_SCOPE_AGENT) <
           (unsigned)NBLOCKS) {
      __builtin_amdgcn_s_sleep(2);
    }
  }
  __syncthreads();
}

// ---------------- fused: prep + split-KV attention + combine ----------------
// grid (x=8, y=64): XCD = id%8 = x = split. Phase-1 stages split x's K/V into
// XCD-local L2 (no cross-XCD traffic). Phase-2 = r11 main loop. Partials cross
// XCDs -> relaxed AGENT-scope atomics (bypass non-coherent L2, coherent at L3).
__global__ __launch_bounds__(256, 2) void attn_fused(
    const float* __restrict__ Q, const float* __restrict__ K,
    const float* __restrict__ V, unsigned short* __restrict__ Kst,
    unsigned short* __restrict__ Vst, unsigned long long* __restrict__ opb,
    float* __restrict__ lp, unsigned int* __restrict__ bar,
    float* __restrict__ O) {
  __shared__ __align__(16) unsigned short kt[8192];
  __shared__ __align__(16) unsigned short vt[8192];
  __shared__ __align__(16) unsigned short pt[4][32 * PSTR];

  const int tid  = threadIdx.x;
  const int wave = tid >> 6;
  const int lane = tid & 63;
  const int m    = lane & 31;
  const int hi   = lane >> 5;
  const int x = blockIdx.x, y = blockIdx.y;
  const int split = x, qtile = y;
  const int qbase = qtile * 128 + wave * 32;

  // Q A-frags (pre-scaled) — independent of phase 1
  short8 qf[8];
  {
    const float* qrow = Q + (size_t)(qbase + m) * DIM + hi * 8;
    #pragma unroll
    for (int cc = 0; cc < 8; cc++) {
      float4 a = *(const float4*)(qrow + cc * 16);
      float4 b = *(const float4*)(qrow + cc * 16 + 4);
      short8 v;
      unsigned int u0 = f2bf2(a.x * SCALE_L2E, a.y * SCALE_L2E);
      unsigned int u1 = f2bf2(a.z * SCALE_L2E, a.w * SCALE_L2E);
      unsigned int u2 = f2bf2(b.x * SCALE_L2E, b.y * SCALE_L2E);
      unsigned int u3 = f2bf2(b.z * SCALE_L2E, b.w * SCALE_L2E);
      v[0] = (short)(u0 & 0xffff); v[1] = (short)(u0 >> 16);
      v[2] = (short)(u1 & 0xffff); v[3] = (short)(u1 >> 16);
      v[4] = (short)(u2 & 0xffff); v[5] = (short)(u2 >> 16);
      v[6] = (short)(u3 & 0xffff); v[7] = (short)(u3 >> 16);
      qf[cc] = v;
    }
  }

  // ---- phase 1: stage this XCD's split. y<32: K tile32 x*32+y ; y>=32: V chunks.
  if (y < 32) {
    const int t32 = x * 32 + y;
    const int r0  = t32 * 32;
    #pragma unroll
    for (int i = 0; i < 4; i++) {
      int idx = i * 256 + tid;
      int r  = idx >> 5;
      int c4 = (idx & 31) << 2;
      int g  = c4 >> 3;
      const float4 f = *(const float4*)(K + (size_t)(r0 + r) * DIM + c4);
      uint2 u = {f2bf2(f.x, f.y), f2bf2(f.z, f.w)};
      *(uint2*)&kt[r * 128 + ((g ^ (r & 7)) << 3) + (c4 & 7)] = u;
    }
    __syncthreads();
    const size_t base = (size_t)t32 * 512;
    #pragma unroll
    for (int e = 0; e < 2; e++) {
      int c  = e * 256 + tid;
      int n  = c & 31;
      int h2 = (c >> 5) & 1;
      int cc = c >> 6;
      int g  = cc * 2 + h2;
      uint4 u = *(const uint4*)&kt[n * 128 + ((g ^ (n & 7)) << 3)];
      *(uint4*)&Kst[(base + (size_t)g * 32 + n) * 8] = u;
    }
  } else {
    #pragma unroll
    for (int e = 0; e < 2; e++) {
      int c    = x * 16384 + (y - 32) * 512 + e * 256 + tid;
      int n    = c & 31;
      int h2   = (c >> 5) & 1;
      int c2   = (c >> 6) & 3;
      int dt   = (c >> 8) & 3;
      int tile = c >> 10;
      const float* src = V + (size_t)(tile * 64 + c2 * 16 + h2 * 8) * DIM + dt * 32 + n;
      float v[8];
      #pragma unroll
      for (int j = 0; j < 8; j++) v[j] = src[(size_t)j * DIM];
      uint4 u;
      u.x = f2bf2(v[0], v[1]); u.y = f2bf2(v[2], v[3]);
      u.z = f2bf2(v[4], v[5]); u.w = f2bf2(v[6], v[7]);
      size_t oc = ((((size_t)(tile * 2 + (c2 >> 1)) * 4 + dt) * 2 + (c2 & 1)) * 2 + h2) * 32 + n;
      *(uint4*)&Vst[oc * 8] = u;
    }
  }
  gbar(&bar[0]);

  // ---- phase 2: r11 main loop (BC=64, sync DMA, 32x32 MFMA) ----
  float lsum[16];
  f32x16 accO[4];
  #pragma unroll
  for (int r = 0; r < 16; r++) lsum[r] = 0.f;
  #pragma unroll
  for (int dt = 0; dt < 4; dt++)
    #pragma unroll
    for (int r = 0; r < 16; r++) accO[dt][r] = 0.f;

  unsigned short* ptw = &pt[wave][0];
  const int tbase32 = split * (SPLITLEN / 32);

  for (int it = 0; it < NT64; it++) {
    const unsigned short* ks = Kst + (size_t)(tbase32 + it * 2) * 4096;
    const unsigned short* vs = Vst + (size_t)(tbase32 + it * 2) * 4096;
    __syncthreads();
    #pragma unroll
    for (int i = 0; i < 4; i++) {
      int ch = wave * 4 + i;
      async_cp16(ks + ch * 512 + lane * 8, (char*)kt + ch * 1024);
      async_cp16(vs + ch * 512 + lane * 8, (char*)vt + ch * 1024);
    }
    __syncthreads();

    f32x16 accS[2];
    #pragma unroll
    for (int kt2 = 0; kt2 < 2; kt2++) {
      f32x16 acc;
      #pragma unroll
      for (int r = 0; r < 16; r++) acc[r] = 0.f;
      #pragma unroll
      for (int cc = 0; cc < 8; cc++) {
        short8 b = *(const short8*)&kt[kt2 * 4096 + ((cc * 2 + hi) * 32 + m) * 8];
        acc = __builtin_amdgcn_mfma_f32_32x32x16_bf16(qf[cc], b, acc, 0, 0, 0);
      }
      accS[kt2] = acc;
    }

    #pragma unroll
    for (int kt2 = 0; kt2 < 2; kt2++) {
      #pragma unroll
      for (int reg = 0; reg < 16; reg++) {
        int row = (reg & 3) + 8 * (reg >> 2) + 4 * hi;
        float p = fast_exp2(accS[kt2][reg]);
        lsum[reg] += p;
        ptw[row * PSTR + kt2 * 32 + m] = f2bf(p);
      }
    }

    short8 ap[4];
    #pragma unroll
    for (int g = 0; g < 4; g++)
      ap[g] = *(const short8*)&ptw[m * PSTR + g * 16 + hi * 8];

    #pragma unroll
    for (int dt = 0; dt < 4; dt++) {
      #pragma unroll
      for (int g = 0; g < 4; g++) {
        short8 b = *(const short8*)&vt[(g >> 1) * 4096 +
                                       ((dt * 4 + (g & 1) * 2 + hi) * 32 + m) * 8];
        accO[dt] = __builtin_amdgcn_mfma_f32_32x32x16_bf16(ap[g], b, accO[dt], 0, 0, 0);
      }
    }
  }

  // epilogue: l-reduce; pack 4 dt-values per reg into one u64; agent-scope store
  #pragma unroll
  for (int reg = 0; reg < 16; reg++) {
    float l = lsum[reg];
    l += __shfl_xor(l, 1);
    l += __shfl_xor(l, 2);
    l += __shfl_xor(l, 4);
    l += __shfl_xor(l, 8);
    l += __shfl_xor(l, 16);
    int qrow = qbase + (reg & 3) + 8 * (reg >> 2) + 4 * hi;
    unsigned long long pk =
        (unsigned long long)f2bf(accO[0][reg]) |
        ((unsigned long long)f2bf(accO[1][reg]) << 16) |
        ((unsigned long long)f2bf(accO[2][reg]) << 32) |
        ((unsigned long long)f2bf(accO[3][reg]) << 48);
    __hip_atomic_store(&opb[((size_t)(split * SEQ + qrow) << 5) + m], pk,
                       __ATOMIC_RELAXED, __HIP_MEMORY_SCOPE_AGENT);
    if (m == 0)
      __hip_atomic_store(&lp[(size_t)split * SEQ + qrow], l,
                         __ATOMIC_RELAXED, __HIP_MEMORY_SCOPE_AGENT);
  }
  gbar(&bar[1]);

  // ---- phase 3: combine. thread -> (qrow, 16-byte window w) ----
  {
    int gid  = (y * 8 + x) * 256 + tid;  // 0..131071
    int qrow = gid >> 4;
    int w    = gid & 15;
    float denom = 0.f;
    float acc[8] = {0.f, 0.f, 0.f, 0.f, 0.f, 0.f, 0.f, 0.f};
    #pragma unroll
    for (int s = 0; s < NSPLIT; s++) {
      denom += __hip_atomic_load(&lp[(size_t)s * SEQ + qrow],
                                 __ATOMIC_RELAXED, __HIP_MEMORY_SCOPE_AGENT);
      const size_t rb = ((size_t)(s * SEQ + qrow) << 5);
      unsigned long long a = __hip_atomic_load(&opb[rb + 2 * w],
                                 __ATOMIC_RELAXED, __HIP_MEMORY_SCOPE_AGENT);
      unsigned long long b = __hip_atomic_load(&opb[rb + 2 * w + 1],
                                 __ATOMIC_RELAXED, __HIP_MEMORY_SCOPE_AGENT);
      #pragma unroll
      for (int j = 0; j < 4; j++) {
        acc[j]     += bf2f((unsigned short)(a >> (16 * j)));
        acc[4 + j] += bf2f((unsigned short)(b >> (16 * j)));
      }
    }
    float inv = 1.f / denom;
    #pragma unroll
    for (int dt = 0; dt < 4; dt++) {
      float2 o2 = {acc[dt] * inv, acc[4 + dt] * inv};
      *(float2*)&O[(size_t)qrow * DIM + dt * 32 + 2 * w] = o2;
    }
  }
}

// ---------- fallback (single-pass 16x16 kernel, used only if ws too small) ----------
#define KSTR 136
#define VSTR 72
#define FPSTR 72
__global__ __launch_bounds__(256, 1) void attn_fwd_fb(
    const float* __restrict__ Q, const float* __restrict__ K,
    const float* __restrict__ V, float* __restrict__ O) {
  __shared__ __align__(16) unsigned short kt[64 * KSTR];
  __shared__ __align__(16) unsigned short vt[DIM * VSTR];
  __shared__ __align__(16) unsigned short pt[4][16 * FPSTR];
  const int tid = threadIdx.x, wave = tid >> 6, lane = tid & 63;
  const int l15 = lane & 15, quad = lane >> 4;
  const int qbase = blockIdx.x * 64 + wave * 16;
  short8 qf[4];
  {
    const float* qrow = Q + (size_t)(qbase + l15) * DIM + quad * 8;
    #pragma unroll
    for (int c = 0; c < 4; c++) {
      short8 v;
      #pragma unroll
      for (int j = 0; j < 8; j++) v[j] = (short)f2bf(qrow[c * 32 + j]);
      qf[c] = v;
    }
  }
  float lsum[4] = {0.f, 0.f, 0.f, 0.f};
  f32x4 o[8];
  const f32x4 fzero = {0.f, 0.f, 0.f, 0.f};
  #pragma unroll
  for (int d = 0; d < 8; d++) o[d] = fzero;
  unsigned short* pw = &pt[wave][0];
  for (int kv0 = 0; kv0 < SEQ; kv0 += 64) {
    __syncthreads();
    #pragma unroll
    for (int i = 0; i < 8; i++) {
      int idx = i * 256 + tid;
      int r = idx >> 5, c4 = (idx & 31) << 2;
      const float4 f = *(const float4*)(K + (size_t)(kv0 + r) * DIM + c4);
      uint2 u = {f2bf2(f.x, f.y), f2bf2(f.z, f.w)};
      *(uint2*)&kt[r * KSTR + c4] = u;
    }
    #pragma unroll
    for (int i = 0; i < 8; i++) {
      int idx = i * 256 + tid;
      int c = idx & 127, g = idx >> 7;
      const float* src = V + (size_t)(kv0 + 4 * g) * DIM + c;
      uint2 u = {f2bf2(src[0], src[DIM]), f2bf2(src[2 * DIM], src[3 * DIM])};
      *(uint2*)&vt[c * VSTR + 4 * g] = u;
    }
    __syncthreads();
    f32x4 s[4];
    #pragma unroll
    for (int blk = 0; blk < 4; blk++) {
      f32x4 acc = fzero;
      const unsigned short* kr = &kt[(blk * 16 + l15) * KSTR + quad * 8];
      #pragma unroll
      for (int c = 0; c < 4; c++)
        acc = __builtin_amdgcn_mfma_f32_16x16x32_bf16(qf[c], *(const short8*)&kr[c * 32], acc, 0, 0, 0);
      s[blk] = acc;
    }
    #pragma unroll
    for (int r = 0; r < 4; r++) {
      #pragma unroll
      for (int blk = 0; blk < 4; blk++) {
        float p = fast_exp2(s[blk][r] * SCALE_L2E);
        lsum[r] += p;
        pw[(quad * 4 + r) * FPSTR + blk * 16 + l15] = f2bf(p);
      }
    }
    short8 ap0 = *(const short8*)&pw[l15 * FPSTR + quad * 8];
    short8 ap1 = *(const short8*)&pw[l15 * FPSTR + 32 + quad * 8];
    #pragma unroll
    for (int d = 0; d < 8; d++) {
      const unsigned short* vr = &vt[(d * 16 + l15) * VSTR + quad * 8];
      o[d] = __builtin_amdgcn_mfma_f32_16x16x32_bf16(ap0, *(const short8*)&vr[0], o[d], 0, 0, 0);
      o[d] = __builtin_amdgcn_mfma_f32_16x16x32_bf16(ap1, *(const short8*)&vr[32], o[d], 0, 0, 0);
    }
  }
  #pragma unroll
  for (int r = 0; r < 4; r++) {
    float l = lsum[r];
    l += __shfl_xor(l, 1); l += __shfl_xor(l, 2);
    l += __shfl_xor(l, 4); l += __shfl_xor(l, 8);
    float inv = 1.f / l;
    float* orow = O + (size_t)(qbase + quad * 4 + r) * DIM + l15;
    #pragma unroll
    for (int d = 0; d < 8; d++) orow[d * 16] = o[d][r] * inv;
  }
}

extern "C" void kernel_launch(void* const* d_in, const int* in_sizes, int n_in,
                              void* d_out, int out_size, void* d_ws, size_t ws_size,
                              hipStream_t stream) {
  const float* Q = (const float*)d_in[0];
  const float* K = (const float*)d_in[1];
  const float* V = (const float*)d_in[2];
  float* O = (float*)d_out;
  if (ws_size >= WS_NEED) {
    char* ws = (char*)d_ws;
    unsigned long long* opb = (unsigned long long*)ws;
    float* lp           = (float*)(ws + LP_BYTE);
    unsigned short* Kst = (unsigned short*)(ws + KST_BYTE);
    unsigned short* Vst = (unsigned short*)(ws + VST_BYTE);
    unsigned int* bar   = (unsigned int*)(ws + BAR_BYTE);
    hipMemsetAsync(bar, 0, 128, stream);  // zero barrier counters (ws is poisoned)
    hipLaunchKernelGGL(attn_fused, dim3(8, 64), dim3(256), 0, stream,
                       Q, K, V, Kst, Vst, opb, lp, bar, O);
  } else {
    hipLaunchKernelGGL(attn_fwd_fb, dim3(SEQ / 64), dim3(256), 0, stream, Q, K, V, O);
  }
}